// Round 17
// baseline (251.315 us; speedup 1.0000x reference)
//
#include <hip/hip_runtime.h>
#include <math.h>

#define B_DIM 128
#define N_DIM 512
#define D_DIM 512
#define H_DIM 256
#define K_SEL 8

typedef _Float16 half8 __attribute__((ext_vector_type(8)));
typedef float    f32x4 __attribute__((ext_vector_type(4)));

__device__ __forceinline__ void gload_lds16(const void* g, void* l) {
    __builtin_amdgcn_global_load_lds((const __attribute__((address_space(1))) void*)g,
                                     (__attribute__((address_space(3))) void*)l, 16, 0, 0);
}

// ---------------- prep W1 -> MFMA-frag-ordered fp16 h/l' tables (proven r15/r16) ------
// w1frag[(c4*16 + ks)*512 + lane*8 + j]: col = c4*16 + (lane&15), k = ks*32 + (lane>>4)*8 + j.
// Split: x = h + l'/2048 + eps, |eps| <= 2^-22|x|.
__global__ __launch_bounds__(512) void prep_w1_kernel(
    const float* __restrict__ W1,          // (512, 256) [k][col]
    _Float16* __restrict__ w1frag_h,
    _Float16* __restrict__ w1frag_l)
{
    const int b    = blockIdx.x;           // 0..255 = c4*16 + ks
    const int c4   = b >> 4;
    const int ks   = b & 15;
    const int lane = threadIdx.x >> 3;     // 0..63
    const int j    = threadIdx.x & 7;
    const int col  = c4 * 16 + (lane & 15);
    const int k    = ks * 32 + (lane >> 4) * 8 + j;
    float x = W1[(size_t)k * H_DIM + col];
    _Float16 h = (_Float16)x;
    float r = x - (float)h;
    size_t o = (size_t)b * 512 + lane * 8 + j;
    w1frag_h[o] = h;
    w1frag_l[o] = (_Float16)(r * 2048.0f);
}

// ---------------- prep X -> MFMA-B-frag-ordered fp16 h/l' tables (d_ws, 128 MiB) ------
// xfrag[(rb*16 + ks)*512 + lane*8 + j]: token = rb*16 + (lane&15), k = ks*32 + (lane>>4)*8 + j
// — exactly the mfma_f32_16x16x32_f16 B-operand layout (r14-verified orientation).
// Reads: each wave consumes 16 rows x 128 B fully (no overfetch); writes coalesced 1 KB.
__global__ __launch_bounds__(512) void prep_x_kernel(
    const float* __restrict__ X,           // (65536, 512)
    _Float16* __restrict__ xfrag_h,
    _Float16* __restrict__ xfrag_l)
{
    const int rb   = blockIdx.x;           // 0..4095 (16-token block)
    const int lane = threadIdx.x & 63;
    const int ks8  = threadIdx.x >> 6;     // 0..7
    const int row  = rb * 16 + (lane & 15);
    const int lg   = lane >> 4;
    #pragma unroll
    for (int kk = 0; kk < 2; ++kk) {
        int ks = ks8 + kk * 8;
        const float* xp = X + (size_t)row * D_DIM + ks * 32 + lg * 8;
        float4 a = *reinterpret_cast<const float4*>(xp);
        float4 b = *reinterpret_cast<const float4*>(xp + 4);
        float e[8] = {a.x, a.y, a.z, a.w, b.x, b.y, b.z, b.w};
        half8 hh, ll;
        #pragma unroll
        for (int j = 0; j < 8; ++j) {
            _Float16 h = (_Float16)e[j];
            float r = e[j] - (float)h;
            hh[j] = h;
            ll[j] = (_Float16)(r * 2048.0f);
        }
        size_t o = ((size_t)rb * 16 + ks) * 512 + lane * 8;
        *reinterpret_cast<half8*>(xfrag_h + o) = hh;
        *reinterpret_cast<half8*>(xfrag_l + o) = ll;
    }
}

// ---------------- FAST scorer: LDS-free, barrier-free, both operands frag-ordered -----
// Wave = 16 tokens x 256 hidden (rb = bid*8 + wave). Per k-step: 2 X-frag + 32 W-frag
// coalesced b128 loads + 48 MFMAs. acc[16] = 64 AGPR; ~118 regs < (512,2)'s measured
// 128 cap. No __syncthreads anywhere: waves drift freely, so MFMA/VALU/VMEM pipes
// overlap across the CU instead of serializing in lockstep (r4-r16's 8700 cyc/step).
// D-layout (r14-verified): token = lane&15, hidden = m*16 + (lane>>4)*4 + r.
__global__ __launch_bounds__(512, 2) void fused_scorer_direct(
    const _Float16* __restrict__ xfrag_h,  // (33554432)
    const _Float16* __restrict__ xfrag_l,
    const _Float16* __restrict__ w1frag_h, // (131072)
    const _Float16* __restrict__ w1frag_l,
    const float* __restrict__ b1,          // (256)
    const float* __restrict__ W2,          // (256)
    const float* __restrict__ b2p,         // scalar
    const float* __restrict__ base_logits, // (512)
    float* __restrict__ logits)            // (65536)
{
    const int lane = threadIdx.x & 63;
    const int wave = threadIdx.x >> 6;
    const int lg   = lane >> 4;
    const int rb   = blockIdx.x * 8 + wave;

    const _Float16* xph = xfrag_h + ((size_t)rb * 16) * 512 + lane * 8;
    const _Float16* xpl = xfrag_l + ((size_t)rb * 16) * 512 + lane * 8;
    const _Float16* wph = w1frag_h + lane * 8;
    const _Float16* wpl = w1frag_l + lane * 8;

    f32x4 acc[16];
    #pragma unroll
    for (int m = 0; m < 16; ++m) acc[m] = (f32x4){0.f, 0.f, 0.f, 0.f};
    const f32x4 z4 = (f32x4){0.f, 0.f, 0.f, 0.f};

    #pragma unroll 4
    for (int ks = 0; ks < 16; ++ks) {
        half8 axh = *reinterpret_cast<const half8*>(xph + ks * 512);
        half8 axl = *reinterpret_cast<const half8*>(xpl + ks * 512);
        #pragma unroll
        for (int m = 0; m < 16; ++m) {
            size_t wo = (size_t)(m * 16 + ks) * 512;
            half8 wh = *reinterpret_cast<const half8*>(wph + wo);
            half8 wl = *reinterpret_cast<const half8*>(wpl + wo);
            acc[m] = __builtin_amdgcn_mfma_f32_16x16x32_f16(wh, axh, acc[m], 0, 0, 0);
            f32x4 t = __builtin_amdgcn_mfma_f32_16x16x32_f16(wh, axl, z4, 0, 0, 0);
            t = __builtin_amdgcn_mfma_f32_16x16x32_f16(wl, axh, t, 0, 0, 0);
            acc[m] += t * (1.0f / 2048.0f);
        }
    }

    // epilogue: z = acc + b1 ; exact GELU ; dot W2 ; reduce over lg ; write
    float part = 0.f;
    #pragma unroll
    for (int m = 0; m < 16; ++m) {
        float4 b1v = *reinterpret_cast<const float4*>(b1 + m * 16 + lg * 4);
        float4 w2v = *reinterpret_cast<const float4*>(W2 + m * 16 + lg * 4);
        float bb[4] = {b1v.x, b1v.y, b1v.z, b1v.w};
        float ww[4] = {w2v.x, w2v.y, w2v.z, w2v.w};
        #pragma unroll
        for (int r = 0; r < 4; ++r) {
            float z = acc[m][r] + bb[r];
            float g = 0.5f * z * (1.0f + erff(z * 0.70710678118654752440f));
            part = fmaf(g, ww[r], part);
        }
    }
    part += __shfl_xor(part, 16, 64);
    part += __shfl_xor(part, 32, 64);
    if (lane < 16) {
        int row = rb * 16 + lane;
        logits[row] = part + b2p[0] + base_logits[row & (N_DIM - 1)];
    }
}

// ---------------- FALLBACK scorer (r16 verbatim, used when ws_size < 128 MiB) ---------
__global__ __launch_bounds__(512, 1) void fused_scorer_mfma(
    const float* __restrict__ X,
    const _Float16* __restrict__ w1frag_h,
    const _Float16* __restrict__ w1frag_l,
    const float* __restrict__ b1,
    const float* __restrict__ W2,
    float* __restrict__ lp)
{
    __shared__ half8 Ah[2][1024], Al[2][1024];
    __shared__ half8 Bh[2][512],  Bl[2][512];

    const int tid  = threadIdx.x;
    const int lane = tid & 63;
    const int wave = tid >> 6;
    const int wm   = (wave >> 1) << 6;
    const int wnx  = wave & 1;
    const int l15  = lane & 15;
    const int lg   = lane >> 4;
    const int rowtile = blockIdx.x & 255;
    const int colhalf = blockIdx.x >> 8;
    const int row0 = rowtile * 256;

    const int rc  = tid & 255;
    const int kc1 = tid >> 8;
    const float* xp = X + (size_t)(row0 + rc) * D_DIM + kc1 * 8;
    const _Float16* bsrc_h = w1frag_h + ((size_t)(colhalf * 8 + (tid >> 6)) * 16) * 512 + (tid & 63) * 8;
    const _Float16* bsrc_l = w1frag_l + ((size_t)(colhalf * 8 + (tid >> 6)) * 16) * 512 + (tid & 63) * 8;

    f32x4 acc[4][4], acc2[4][4];
    #pragma unroll
    for (int mi = 0; mi < 4; ++mi)
        #pragma unroll
        for (int nj = 0; nj < 4; ++nj) {
            acc[mi][nj]  = (f32x4){0.f, 0.f, 0.f, 0.f};
            acc2[mi][nj] = (f32x4){0.f, 0.f, 0.f, 0.f};
        }

    float4 xv[4];
    auto load_a = [&](int k0) {
        xv[0] = *reinterpret_cast<const float4*>(xp + k0);
        xv[1] = *reinterpret_cast<const float4*>(xp + k0 + 4);
        xv[2] = *reinterpret_cast<const float4*>(xp + k0 + 16);
        xv[3] = *reinterpret_cast<const float4*>(xp + k0 + 20);
    };
    auto split_write = [&](int buf) {
        #pragma unroll
        for (int q = 0; q < 2; ++q) {
            float e[8] = {xv[2*q].x, xv[2*q].y, xv[2*q].z, xv[2*q].w,
                          xv[2*q+1].x, xv[2*q+1].y, xv[2*q+1].z, xv[2*q+1].w};
            half8 hh, ll;
            #pragma unroll
            for (int j = 0; j < 8; ++j) {
                _Float16 h = (_Float16)e[j];
                float r = e[j] - (float)h;
                hh[j] = h;
                ll[j] = (_Float16)(r * 2048.0f);
            }
            Ah[buf][tid + q * 512] = hh;
            Al[buf][tid + q * 512] = ll;
        }
    };
    auto stage_b = [&](int buf, int ks) {
        gload_lds16(bsrc_h + (size_t)ks * 512, &Bh[buf][tid]);
        gload_lds16(bsrc_l + (size_t)ks * 512, &Bl[buf][tid]);
    };

    load_a(0);
    stage_b(0, 0);
    split_write(0);
    load_a(32);
    __syncthreads();

    for (int ks = 0; ks < 16; ++ks) {
        const int buf = ks & 1, nbuf = buf ^ 1;
        if (ks < 15) {
            stage_b(nbuf, ks + 1);
            split_write(nbuf);
            if (ks < 14) load_a((ks + 2) * 32);
        }
        half8 fbh[4], fbl[4];
        #pragma unroll
        for (int nj = 0; nj < 4; ++nj) {
            int cb = (wnx * 4 + nj) * 64 + lane;
            fbh[nj] = Bh[buf][cb];
            fbl[nj] = Bl[buf][cb];
        }
        #pragma unroll
        for (int p = 0; p < 2; ++p) {
            half8 fah[2], fal[2];
            #pragma unroll
            for (int m = 0; m < 2; ++m) {
                int ca = lg * 256 + wm + (p * 2 + m) * 16 + l15;
                fah[m] = Ah[buf][ca];
                fal[m] = Al[buf][ca];
            }
            #pragma unroll
            for (int nj = 0; nj < 4; ++nj)
                #pragma unroll
                for (int m = 0; m < 2; ++m) {
                    int mi = p * 2 + m;
                    acc[mi][nj]  = __builtin_amdgcn_mfma_f32_16x16x32_f16(fah[m], fbh[nj], acc[mi][nj],  0, 0, 0);
                    acc2[mi][nj] = __builtin_amdgcn_mfma_f32_16x16x32_f16(fah[m], fbl[nj], acc2[mi][nj], 0, 0, 0);
                    acc2[mi][nj] = __builtin_amdgcn_mfma_f32_16x16x32_f16(fal[m], fbh[nj], acc2[mi][nj], 0, 0, 0);
                }
        }
        __syncthreads();
    }

    float b1v[4], w2v[4];
    #pragma unroll
    for (int nj = 0; nj < 4; ++nj) {
        int col = colhalf * 128 + wnx * 64 + nj * 16 + l15;
        b1v[nj] = b1[col];
        w2v[nj] = W2[col];
    }
    float part[4][4];
    #pragma unroll
    for (int mi = 0; mi < 4; ++mi)
        #pragma unroll
        for (int r = 0; r < 4; ++r)
            part[mi][r] = 0.f;
    #pragma unroll
    for (int mi = 0; mi < 4; ++mi)
        #pragma unroll
        for (int nj = 0; nj < 4; ++nj)
            #pragma unroll
            for (int r = 0; r < 4; ++r) {
                float z = acc[mi][nj][r] + acc2[mi][nj][r] * (1.0f / 2048.0f) + b1v[nj];
                float g = 0.5f * z * (1.0f + erff(z * 0.70710678118654752440f));
                part[mi][r] = fmaf(g, w2v[nj], part[mi][r]);
            }
    float* red = reinterpret_cast<float*>(&Ah[0][0]);
    #pragma unroll
    for (int mi = 0; mi < 4; ++mi)
        #pragma unroll
        for (int r = 0; r < 4; ++r) {
            float v = part[mi][r];
            v += __shfl_xor(v, 1, 16);
            v += __shfl_xor(v, 2, 16);
            v += __shfl_xor(v, 4, 16);
            v += __shfl_xor(v, 8, 16);
            if (l15 == 0)
                red[wnx * 256 + wm + mi * 16 + lg * 4 + r] = v;
        }
    __syncthreads();
    if (tid < 256)
        lp[(size_t)colhalf * 65536 + row0 + tid] = red[tid] + red[256 + tid];
}

// ---------------- softmax + top-8 (logits input — fast path) -------------------------
__global__ __launch_bounds__(256) void softmax_topk_logits(
    const float* __restrict__ logits,
    float* __restrict__ out_mask,
    float* __restrict__ out_importance,
    float* __restrict__ out_indices)
{
    const int b = blockIdx.x;
    const int tid = threadIdx.x;
    __shared__ float probs[N_DIM];
    __shared__ float redf[4];
    __shared__ int   redi[4];
    __shared__ int   sel_idx[K_SEL];

    float l0 = logits[b * N_DIM + tid];
    float l1 = logits[b * N_DIM + tid + 256];

    float m = fmaxf(l0, l1);
    #pragma unroll
    for (int s = 32; s >= 1; s >>= 1) m = fmaxf(m, __shfl_xor(m, s, 64));
    if ((tid & 63) == 0) redf[tid >> 6] = m;
    __syncthreads();
    float gm = fmaxf(fmaxf(redf[0], redf[1]), fmaxf(redf[2], redf[3]));
    __syncthreads();

    float e0 = expf(l0 - gm), e1 = expf(l1 - gm);
    float ssum = e0 + e1;
    #pragma unroll
    for (int s = 32; s >= 1; s >>= 1) ssum += __shfl_xor(ssum, s, 64);
    if ((tid & 63) == 0) redf[tid >> 6] = ssum;
    __syncthreads();
    float denom = redf[0] + redf[1] + redf[2] + redf[3];
    float p0 = e0 / denom, p1 = e1 / denom;
    probs[tid] = p0;
    probs[tid + 256] = p1;
    out_importance[b * N_DIM + tid] = p0;
    out_importance[b * N_DIM + tid + 256] = p1;
    __syncthreads();

    for (int it = 0; it < K_SEL; ++it) {
        float v0 = probs[tid]; int i0 = tid;
        float v1 = probs[tid + 256];
        if (v1 > v0) { v0 = v1; i0 = tid + 256; }
        #pragma unroll
        for (int s = 32; s >= 1; s >>= 1) {
            float ov = __shfl_xor(v0, s, 64);
            int   oi = __shfl_xor(i0, s, 64);
            if (ov > v0 || (ov == v0 && oi < i0)) { v0 = ov; i0 = oi; }
        }
        if ((tid & 63) == 0) { redf[tid >> 6] = v0; redi[tid >> 6] = i0; }
        __syncthreads();
        if (tid == 0) {
            float bv = redf[0]; int bi = redi[0];
            for (int w = 1; w < 4; ++w)
                if (redf[w] > bv || (redf[w] == bv && redi[w] < bi)) { bv = redf[w]; bi = redi[w]; }
            sel_idx[it] = bi;
            probs[bi] = -1.0f;
        }
        __syncthreads();
    }

    float mk0 = 0.f, mk1 = 0.f;
    #pragma unroll
    for (int i = 0; i < K_SEL; ++i) {
        if (sel_idx[i] == tid)       mk0 = 1.f;
        if (sel_idx[i] == tid + 256) mk1 = 1.f;
    }
    out_mask[b * N_DIM + tid] = mk0;
    out_mask[b * N_DIM + tid + 256] = mk1;

    if (tid < K_SEL) out_indices[b * K_SEL + tid] = (float)sel_idx[tid];
}

// ---------------- softmax + top-8 (lp input — fallback path, r16 verbatim) ------------
__global__ __launch_bounds__(256) void softmax_topk_lp(
    const float* __restrict__ lp,
    const float* __restrict__ b2p,
    const float* __restrict__ base_logits,
    float* __restrict__ out_mask,
    float* __restrict__ out_importance,
    float* __restrict__ out_indices)
{
    const int b = blockIdx.x;
    const int tid = threadIdx.x;
    __shared__ float probs[N_DIM];
    __shared__ float redf[4];
    __shared__ int   redi[4];
    __shared__ int   sel_idx[K_SEL];

    const float b2v = b2p[0];
    int i0g = b * N_DIM + tid;
    int i1g = i0g + 256;
    float l0 = lp[i0g] + lp[65536 + i0g] + b2v + base_logits[tid];
    float l1 = lp[i1g] + lp[65536 + i1g] + b2v + base_logits[tid + 256];

    float m = fmaxf(l0, l1);
    #pragma unroll
    for (int s = 32; s >= 1; s >>= 1) m = fmaxf(m, __shfl_xor(m, s, 64));
    if ((tid & 63) == 0) redf[tid >> 6] = m;
    __syncthreads();
    float gm = fmaxf(fmaxf(redf[0], redf[1]), fmaxf(redf[2], redf[3]));
    __syncthreads();

    float e0 = expf(l0 - gm), e1 = expf(l1 - gm);
    float ssum = e0 + e1;
    #pragma unroll
    for (int s = 32; s >= 1; s >>= 1) ssum += __shfl_xor(ssum, s, 64);
    if ((tid & 63) == 0) redf[tid >> 6] = ssum;
    __syncthreads();
    float denom = redf[0] + redf[1] + redf[2] + redf[3];
    float p0 = e0 / denom, p1 = e1 / denom;
    probs[tid] = p0;
    probs[tid + 256] = p1;
    out_importance[b * N_DIM + tid] = p0;
    out_importance[b * N_DIM + tid + 256] = p1;
    __syncthreads();

    for (int it = 0; it < K_SEL; ++it) {
        float v0 = probs[tid]; int i0 = tid;
        float v1 = probs[tid + 256];
        if (v1 > v0) { v0 = v1; i0 = tid + 256; }
        #pragma unroll
        for (int s = 32; s >= 1; s >>= 1) {
            float ov = __shfl_xor(v0, s, 64);
            int   oi = __shfl_xor(i0, s, 64);
            if (ov > v0 || (ov == v0 && oi < i0)) { v0 = ov; i0 = oi; }
        }
        if ((tid & 63) == 0) { redf[tid >> 6] = v0; redi[tid >> 6] = i0; }
        __syncthreads();
        if (tid == 0) {
            float bv = redf[0]; int bi = redi[0];
            for (int w = 1; w < 4; ++w)
                if (redf[w] > bv || (redf[w] == bv && redi[w] < bi)) { bv = redf[w]; bi = redi[w]; }
            sel_idx[it] = bi;
            probs[bi] = -1.0f;
        }
        __syncthreads();
    }

    float mk0 = 0.f, mk1 = 0.f;
    #pragma unroll
    for (int i = 0; i < K_SEL; ++i) {
        if (sel_idx[i] == tid)       mk0 = 1.f;
        if (sel_idx[i] == tid + 256) mk1 = 1.f;
    }
    out_mask[b * N_DIM + tid] = mk0;
    out_mask[b * N_DIM + tid + 256] = mk1;

    if (tid < K_SEL) out_indices[b * K_SEL + tid] = (float)sel_idx[tid];
}

// ---------------- gather selected rows (overwrites d_out scratch last) ----------------
__global__ __launch_bounds__(256) void gather_kernel(
    const float* __restrict__ X,
    const float* __restrict__ out_indices,
    float* __restrict__ out_selected)
{
    const int b = blockIdx.x;
    const int tid = threadIdx.x;
    __shared__ int sel[K_SEL];
    if (tid < K_SEL) sel[tid] = (int)out_indices[b * K_SEL + tid];
    __syncthreads();
    #pragma unroll
    for (int i = 0; i < 4; ++i) {
        int f = tid + 256 * i;
        int ki = f >> 7;
        int c4 = f & 127;
        float4 v = reinterpret_cast<const float4*>(
            X + ((size_t)b * N_DIM + sel[ki]) * D_DIM)[c4];
        reinterpret_cast<float4*>(
            out_selected + ((size_t)b * K_SEL + ki) * D_DIM)[c4] = v;
    }
}

extern "C" void kernel_launch(void* const* d_in, const int* in_sizes, int n_in,
                              void* d_out, int out_size, void* d_ws, size_t ws_size,
                              hipStream_t stream) {
    const float* X           = (const float*)d_in[0];
    const float* W1          = (const float*)d_in[1];
    const float* b1          = (const float*)d_in[2];
    const float* W2          = (const float*)d_in[3];
    const float* b2          = (const float*)d_in[4];
    const float* base_logits = (const float*)d_in[5];

    float* out            = (float*)d_out;
    float* out_selected   = out;                                  // 128*8*512 = 524288
    float* out_mask       = out_selected + B_DIM * K_SEL * D_DIM; // 128*512
    float* out_importance = out_mask + B_DIM * N_DIM;             // 128*512
    float* out_indices    = out_importance + B_DIM * N_DIM;       // 128*8

    // d_out scratch (gather overwrites out_selected last):
    //   fast:    [0, 65536) logits f32
    //   fallback:[0, 131072) lp 2x65536 f32
    //   both:    [131072, 196608) w1frag_h ; [196608, 262144) w1frag_l (halfs)
    _Float16* w1frag_h = (_Float16*)(out_selected + 131072);
    _Float16* w1frag_l = (_Float16*)(out_selected + 196608);

    hipLaunchKernelGGL(prep_w1_kernel, dim3(256), dim3(512), 0, stream,
                       W1, w1frag_h, w1frag_l);

    const size_t XFRAG_ELEMS = (size_t)65536 * 512;               // 33554432 halfs/table
    const size_t WS_NEEDED   = XFRAG_ELEMS * 2 * sizeof(_Float16); // 128 MiB

    if (ws_size >= WS_NEEDED) {
        // ---- fast path: frag-order X, then LDS-free barrier-free scorer ----
        _Float16* xfrag_h = (_Float16*)d_ws;
        _Float16* xfrag_l = xfrag_h + XFRAG_ELEMS;
        float* logits = out_selected;
        hipLaunchKernelGGL(prep_x_kernel, dim3(4096), dim3(512), 0, stream,
                           X, xfrag_h, xfrag_l);
        hipLaunchKernelGGL(fused_scorer_direct, dim3(512), dim3(512), 0, stream,
                           xfrag_h, xfrag_l, w1frag_h, w1frag_l,
                           b1, W2, b2, base_logits, logits);
        hipLaunchKernelGGL(softmax_topk_logits, dim3(B_DIM), dim3(256), 0, stream,
                           logits, out_mask, out_importance, out_indices);
    } else {
        // ---- fallback: r16 LDS-staged scorer ----
        float* lp = out_selected;
        hipLaunchKernelGGL(fused_scorer_mfma, dim3(512), dim3(512), 0, stream,
                           X, w1frag_h, w1frag_l, b1, W2, lp);
        hipLaunchKernelGGL(softmax_topk_lp, dim3(B_DIM), dim3(256), 0, stream,
                           lp, b2, base_logits, out_mask, out_importance, out_indices);
    }

    hipLaunchKernelGGL(gather_kernel, dim3(B_DIM), dim3(256), 0, stream,
                       X, out_indices, out_selected);
}

// Round 18
// 211.162 us; speedup vs baseline: 1.1902x; 1.1902x over previous
//
#include <hip/hip_runtime.h>
#include <math.h>

#define B_DIM 128
#define N_DIM 512
#define D_DIM 512
#define H_DIM 256
#define K_SEL 8

typedef _Float16 half8 __attribute__((ext_vector_type(8)));
typedef float    f32x4 __attribute__((ext_vector_type(4)));

__device__ __forceinline__ void gload_lds16(const void* g, void* l) {
    __builtin_amdgcn_global_load_lds((const __attribute__((address_space(1))) void*)g,
                                     (__attribute__((address_space(3))) void*)l, 16, 0, 0);
}

// ---------------- prep W1 -> MFMA-frag-ordered fp16 h/l' tables (proven r15-r17) ------
// w1frag[(c4*16 + ks)*512 + lane*8 + j]: col = c4*16 + (lane&15), k = ks*32 + (lane>>4)*8 + j.
// Split: x = h + l'/2048 + eps, |eps| <= 2^-22|x|.
__global__ __launch_bounds__(512) void prep_w1_kernel(
    const float* __restrict__ W1,          // (512, 256) [k][col]
    _Float16* __restrict__ w1frag_h,
    _Float16* __restrict__ w1frag_l)
{
    const int b    = blockIdx.x;           // 0..255 = c4*16 + ks
    const int c4   = b >> 4;
    const int ks   = b & 15;
    const int lane = threadIdx.x >> 3;     // 0..63
    const int j    = threadIdx.x & 7;
    const int col  = c4 * 16 + (lane & 15);
    const int k    = ks * 32 + (lane >> 4) * 8 + j;
    float x = W1[(size_t)k * H_DIM + col];
    _Float16 h = (_Float16)x;
    float r = x - (float)h;
    size_t o = (size_t)b * 512 + lane * 8 + j;
    w1frag_h[o] = h;
    w1frag_l[o] = (_Float16)(r * 2048.0f);
}

// ---------------- scorer: W fully LDS-resident, barrier-free main loop ----------------
// Synthesis of r4-r17: barriers serialize the pipes (~110 us floor); barrier-free
// fails only if an operand street-fights the cache (r17: W thrash). Fix: each WG owns
// a 64-col W slice = 128 KB = ALL of it in LDS, staged once (frag-ordered DMA),
// ONE barrier, then a drift-free-running main loop:
//   per wave (32 tokens x 64 cols), per k-step: 2 X global loads (2-deep prefetch,
//   in-reg fp16 h/l' split — r14-verified B-operand orientation) + 8 conflict-free
//   ds_read_b128 (W frags, shared by 2 token-groups) + 24 MFMAs (dual-acc).
// Grid: 1024 WGs = 4 col-quarters x 256; wave w of WG handles tokens (wgq*8+w)*32..+31.
// Output: partial logits lp[quarter][token]; softmax sums 4 quarters + b2 + base.
// D-layout (r14/r17-verified): token = lane&15, hidden = m*16 + (lane>>4)*4 + r.
__global__ __launch_bounds__(512, 1) void fused_scorer_wlds(
    const float* __restrict__ X,           // (65536, 512)
    const _Float16* __restrict__ w1frag_h, // (131072) frag-ordered
    const _Float16* __restrict__ w1frag_l,
    const float* __restrict__ b1,          // (256)
    const float* __restrict__ W2,          // (256)
    float* __restrict__ lp)                // (4, 65536) partial logits
{
    __shared__ half8 Wh[4096], Wl[4096];   // [ (m*16+ks)*64 + lane ] -> 64 KB + 64 KB

    const int tid  = threadIdx.x;
    const int lane = tid & 63;
    const int wave = tid >> 6;             // 0..7
    const int l15  = lane & 15;
    const int lg   = lane >> 4;            // 0..3
    const int quarter = blockIdx.x >> 8;   // 0..3
    const int wgq     = blockIdx.x & 255;
    const int tok0 = (wgq * 8 + wave) * 32;

    // ---- stage the 64-col W slice once: 128 chunks of 1 KB, frag-ordered source ----
    #pragma unroll
    for (int c = wave; c < 64; c += 8) {   // c = m*16 + ks ; global chunk = quarter*64+c
        size_t so = ((size_t)(quarter * 64 + c)) * 512 + lane * 8;
        gload_lds16(w1frag_h + so, &Wh[c * 64 + lane]);
        gload_lds16(w1frag_l + so, &Wl[c * 64 + lane]);
    }

    f32x4 acc[4][2], acc2[4][2];           // [m][token-group]
    #pragma unroll
    for (int m = 0; m < 4; ++m)
        #pragma unroll
        for (int tg = 0; tg < 2; ++tg) {
            acc[m][tg]  = (f32x4){0.f, 0.f, 0.f, 0.f};
            acc2[m][tg] = (f32x4){0.f, 0.f, 0.f, 0.f};
        }

    // X bases: token-group 0 rows tok0+l15, group 1 rows tok0+16+l15; k = ks*32+lg*8
    const float* xp0 = X + (size_t)(tok0 + l15) * D_DIM + lg * 8;
    const float* xp1 = xp0 + (size_t)16 * D_DIM;

    auto split8 = [&](float4 a, float4 b, half8& hh, half8& ll) {
        float e[8] = {a.x, a.y, a.z, a.w, b.x, b.y, b.z, b.w};
        #pragma unroll
        for (int j = 0; j < 8; ++j) {
            _Float16 h = (_Float16)e[j];
            float r = e[j] - (float)h;
            hh[j] = h;
            ll[j] = (_Float16)(r * 2048.0f);
        }
    };

    // 2-deep X prefetch
    float4 xv[2][2][2];                    // [buf][tg][lo/hi]
    xv[0][0][0] = *reinterpret_cast<const float4*>(xp0);
    xv[0][0][1] = *reinterpret_cast<const float4*>(xp0 + 4);
    xv[0][1][0] = *reinterpret_cast<const float4*>(xp1);
    xv[0][1][1] = *reinterpret_cast<const float4*>(xp1 + 4);
    xv[1][0][0] = *reinterpret_cast<const float4*>(xp0 + 32);
    xv[1][0][1] = *reinterpret_cast<const float4*>(xp0 + 36);
    xv[1][1][0] = *reinterpret_cast<const float4*>(xp1 + 32);
    xv[1][1][1] = *reinterpret_cast<const float4*>(xp1 + 36);

    __syncthreads();                       // W slice ready; ONLY barrier in the kernel

    for (int ks = 0; ks < 16; ++ks) {
        const int buf = ks & 1;
        half8 bxh[2], bxl[2];
        split8(xv[buf][0][0], xv[buf][0][1], bxh[0], bxl[0]);
        split8(xv[buf][1][0], xv[buf][1][1], bxh[1], bxl[1]);
        if (ks < 14) {                     // refill consumed buffer with ks+2
            const int ko = (ks + 2) * 32;
            xv[buf][0][0] = *reinterpret_cast<const float4*>(xp0 + ko);
            xv[buf][0][1] = *reinterpret_cast<const float4*>(xp0 + ko + 4);
            xv[buf][1][0] = *reinterpret_cast<const float4*>(xp1 + ko);
            xv[buf][1][1] = *reinterpret_cast<const float4*>(xp1 + ko + 4);
        }
        #pragma unroll
        for (int m = 0; m < 4; ++m) {
            const int c = (m * 16 + ks) * 64 + lane;
            half8 wh = Wh[c];
            half8 wl = Wl[c];
            #pragma unroll
            for (int tg = 0; tg < 2; ++tg) {
                acc[m][tg]  = __builtin_amdgcn_mfma_f32_16x16x32_f16(wh, bxh[tg], acc[m][tg],  0, 0, 0);
                acc2[m][tg] = __builtin_amdgcn_mfma_f32_16x16x32_f16(wh, bxl[tg], acc2[m][tg], 0, 0, 0);
                acc2[m][tg] = __builtin_amdgcn_mfma_f32_16x16x32_f16(wl, bxh[tg], acc2[m][tg], 0, 0, 0);
            }
        }
    }

    // ---- epilogue: z = acc + acc2/2048 + b1 ; exact GELU ; dot W2 ; reduce over lg ----
    float part[2] = {0.f, 0.f};
    #pragma unroll
    for (int m = 0; m < 4; ++m) {
        const int col4 = quarter * 64 + m * 16 + lg * 4;
        float4 b1v = *reinterpret_cast<const float4*>(b1 + col4);
        float4 w2v = *reinterpret_cast<const float4*>(W2 + col4);
        float bb[4] = {b1v.x, b1v.y, b1v.z, b1v.w};
        float ww[4] = {w2v.x, w2v.y, w2v.z, w2v.w};
        #pragma unroll
        for (int tg = 0; tg < 2; ++tg)
            #pragma unroll
            for (int r = 0; r < 4; ++r) {
                float z = acc[m][tg][r] + acc2[m][tg][r] * (1.0f / 2048.0f) + bb[r];
                float g = 0.5f * z * (1.0f + erff(z * 0.70710678118654752440f));
                part[tg] = fmaf(g, ww[r], part[tg]);
            }
    }
    #pragma unroll
    for (int tg = 0; tg < 2; ++tg) {
        float v = part[tg];
        v += __shfl_xor(v, 16, 64);
        v += __shfl_xor(v, 32, 64);
        if (lane < 16)
            lp[(size_t)quarter * 65536 + tok0 + tg * 16 + lane] = v;
    }
}

// ---------------- softmax + top-8 + mask/importance/indices (sums 4 lp slices) --------
__global__ __launch_bounds__(256) void softmax_topk_kernel(
    const float* __restrict__ lp,          // (4, 65536)
    const float* __restrict__ b2p,
    const float* __restrict__ base_logits,
    float* __restrict__ out_mask,
    float* __restrict__ out_importance,
    float* __restrict__ out_indices)
{
    const int b = blockIdx.x;
    const int tid = threadIdx.x;
    __shared__ float probs[N_DIM];
    __shared__ float redf[4];
    __shared__ int   redi[4];
    __shared__ int   sel_idx[K_SEL];

    const float b2v = b2p[0];
    int i0g = b * N_DIM + tid;
    int i1g = i0g + 256;
    float l0 = (lp[i0g] + lp[65536 + i0g]) + (lp[131072 + i0g] + lp[196608 + i0g]);
    float l1 = (lp[i1g] + lp[65536 + i1g]) + (lp[131072 + i1g] + lp[196608 + i1g]);
    l0 += b2v + base_logits[tid];
    l1 += b2v + base_logits[tid + 256];

    float m = fmaxf(l0, l1);
    #pragma unroll
    for (int s = 32; s >= 1; s >>= 1) m = fmaxf(m, __shfl_xor(m, s, 64));
    if ((tid & 63) == 0) redf[tid >> 6] = m;
    __syncthreads();
    float gm = fmaxf(fmaxf(redf[0], redf[1]), fmaxf(redf[2], redf[3]));
    __syncthreads();

    float e0 = expf(l0 - gm), e1 = expf(l1 - gm);
    float ssum = e0 + e1;
    #pragma unroll
    for (int s = 32; s >= 1; s >>= 1) ssum += __shfl_xor(ssum, s, 64);
    if ((tid & 63) == 0) redf[tid >> 6] = ssum;
    __syncthreads();
    float denom = redf[0] + redf[1] + redf[2] + redf[3];
    float p0 = e0 / denom, p1 = e1 / denom;
    probs[tid] = p0;
    probs[tid + 256] = p1;
    out_importance[b * N_DIM + tid] = p0;
    out_importance[b * N_DIM + tid + 256] = p1;
    __syncthreads();

    for (int it = 0; it < K_SEL; ++it) {
        float v0 = probs[tid]; int i0 = tid;
        float v1 = probs[tid + 256];
        if (v1 > v0) { v0 = v1; i0 = tid + 256; }
        #pragma unroll
        for (int s = 32; s >= 1; s >>= 1) {
            float ov = __shfl_xor(v0, s, 64);
            int   oi = __shfl_xor(i0, s, 64);
            if (ov > v0 || (ov == v0 && oi < i0)) { v0 = ov; i0 = oi; }
        }
        if ((tid & 63) == 0) { redf[tid >> 6] = v0; redi[tid >> 6] = i0; }
        __syncthreads();
        if (tid == 0) {
            float bv = redf[0]; int bi = redi[0];
            for (int w = 1; w < 4; ++w)
                if (redf[w] > bv || (redf[w] == bv && redi[w] < bi)) { bv = redf[w]; bi = redi[w]; }
            sel_idx[it] = bi;
            probs[bi] = -1.0f;
        }
        __syncthreads();
    }

    float mk0 = 0.f, mk1 = 0.f;
    #pragma unroll
    for (int i = 0; i < K_SEL; ++i) {
        if (sel_idx[i] == tid)       mk0 = 1.f;
        if (sel_idx[i] == tid + 256) mk1 = 1.f;
    }
    out_mask[b * N_DIM + tid] = mk0;
    out_mask[b * N_DIM + tid + 256] = mk1;

    if (tid < K_SEL) out_indices[b * K_SEL + tid] = (float)sel_idx[tid];
}

// ---------------- gather selected rows (overwrites d_out scratch last) ----------------
__global__ __launch_bounds__(256) void gather_kernel(
    const float* __restrict__ X,
    const float* __restrict__ out_indices,
    float* __restrict__ out_selected)
{
    const int b = blockIdx.x;
    const int tid = threadIdx.x;
    __shared__ int sel[K_SEL];
    if (tid < K_SEL) sel[tid] = (int)out_indices[b * K_SEL + tid];
    __syncthreads();
    #pragma unroll
    for (int i = 0; i < 4; ++i) {
        int f = tid + 256 * i;
        int ki = f >> 7;
        int c4 = f & 127;
        float4 v = reinterpret_cast<const float4*>(
            X + ((size_t)b * N_DIM + sel[ki]) * D_DIM)[c4];
        reinterpret_cast<float4*>(
            out_selected + ((size_t)b * K_SEL + ki) * D_DIM)[c4] = v;
    }
}

extern "C" void kernel_launch(void* const* d_in, const int* in_sizes, int n_in,
                              void* d_out, int out_size, void* d_ws, size_t ws_size,
                              hipStream_t stream) {
    const float* X           = (const float*)d_in[0];
    const float* W1          = (const float*)d_in[1];
    const float* b1          = (const float*)d_in[2];
    const float* W2          = (const float*)d_in[3];
    const float* b2          = (const float*)d_in[4];
    const float* base_logits = (const float*)d_in[5];

    float* out            = (float*)d_out;
    float* out_selected   = out;                                  // 128*8*512 = 524288
    float* out_mask       = out_selected + B_DIM * K_SEL * D_DIM; // 128*512
    float* out_importance = out_mask + B_DIM * N_DIM;             // 128*512
    float* out_indices    = out_importance + B_DIM * N_DIM;       // 128*8

    // d_out scratch (gather overwrites out_selected last):
    //   [0      , 262144) lp: 4 x 65536 f32
    //   [262144 , 327680) w1frag_h (131072 halfs)
    //   [327680 , 393216) w1frag_l (131072 halfs)
    float*    lp       = out_selected;
    _Float16* w1frag_h = (_Float16*)(out_selected + 262144);
    _Float16* w1frag_l = (_Float16*)(out_selected + 327680);

    hipLaunchKernelGGL(prep_w1_kernel, dim3(256), dim3(512), 0, stream,
                       W1, w1frag_h, w1frag_l);
    hipLaunchKernelGGL(fused_scorer_wlds, dim3(1024), dim3(512), 0, stream,
                       X, w1frag_h, w1frag_l, b1, W2, lp);
    hipLaunchKernelGGL(softmax_topk_kernel, dim3(B_DIM), dim3(256), 0, stream,
                       lp, b2, base_logits, out_mask, out_importance, out_indices);
    hipLaunchKernelGGL(gather_kernel, dim3(B_DIM), dim3(256), 0, stream,
                       X, out_indices, out_selected);
}

// Round 19
// 118.969 us; speedup vs baseline: 2.1124x; 1.7749x over previous
//
#include <hip/hip_runtime.h>
#include <math.h>

#define B_DIM 128
#define N_DIM 512
#define D_DIM 512
#define H_DIM 256
#define K_SEL 8

typedef _Float16 half8 __attribute__((ext_vector_type(8)));
typedef float    f32x4 __attribute__((ext_vector_type(4)));

__device__ __forceinline__ void gload_lds16(const void* g, void* l) {
    __builtin_amdgcn_global_load_lds((const __attribute__((address_space(1))) void*)g,
                                     (__attribute__((address_space(3))) void*)l, 16, 0, 0);
}

// ---------------- prep W1 -> MFMA-frag-ordered fp16 h/l' tables (proven r15-r18) ------
// w1frag[(c4*16 + ks)*512 + lane*8 + j]: col = c4*16 + (lane&15), k = ks*32 + (lane>>4)*8 + j.
// Split: x = h + l'/2048 + eps, |eps| <= 2^-22|x|.
__global__ __launch_bounds__(512) void prep_w1_kernel(
    const float* __restrict__ W1,          // (512, 256) [k][col]
    _Float16* __restrict__ w1frag_h,
    _Float16* __restrict__ w1frag_l)
{
    const int b    = blockIdx.x;           // 0..255 = c4*16 + ks
    const int c4   = b >> 4;
    const int ks   = b & 15;
    const int lane = threadIdx.x >> 3;     // 0..63
    const int j    = threadIdx.x & 7;
    const int col  = c4 * 16 + (lane & 15);
    const int k    = ks * 32 + (lane >> 4) * 8 + j;
    float x = W1[(size_t)k * H_DIM + col];
    _Float16 h = (_Float16)x;
    float r = x - (float)h;
    size_t o = (size_t)b * 512 + lane * 8 + j;
    w1frag_h[o] = h;
    w1frag_l[o] = (_Float16)(r * 2048.0f);
}

// ---------------- scorer: W LDS-resident, barrier-free loop, STATIC prefetch bufs -----
// r18's design (W 64-col slice fully in LDS, staged once; X direct-from-global as the
// MFMA B-operand, in-reg fp16 h/l' split; no barriers in the main loop) was correct
// but xv[buf][..] used a RUNTIME buf index -> compiler allocated it in scratch
// (WRITE_SIZE 346 MB, rule #20). Fix: unroll k-loop by 2 with NAMED xvA/xvB buffers —
// every access compile-time-constant -> registers.
// Grid: 1024 WGs = 4 col-quarters x 256; wave = 32 tokens x 64 cols; 24 MFMA/k-step.
// D-layout (r14/r17-verified): token = lane&15, hidden = m*16 + (lane>>4)*4 + r.
__global__ __launch_bounds__(512, 1) void fused_scorer_wlds(
    const float* __restrict__ X,           // (65536, 512)
    const _Float16* __restrict__ w1frag_h, // (131072) frag-ordered
    const _Float16* __restrict__ w1frag_l,
    const float* __restrict__ b1,          // (256)
    const float* __restrict__ W2,          // (256)
    float* __restrict__ lp)                // (4, 65536) partial logits
{
    __shared__ half8 Wh[4096], Wl[4096];   // [ (m*16+ks)*64 + lane ] -> 64 KB + 64 KB

    const int tid  = threadIdx.x;
    const int lane = tid & 63;
    const int wave = tid >> 6;             // 0..7
    const int l15  = lane & 15;
    const int lg   = lane >> 4;            // 0..3
    const int quarter = blockIdx.x >> 8;   // 0..3
    const int wgq     = blockIdx.x & 255;
    const int tok0 = (wgq * 8 + wave) * 32;

    // ---- stage the 64-col W slice once: 128 chunks of 1 KB, frag-ordered source ----
    #pragma unroll
    for (int c = wave; c < 64; c += 8) {   // c = m*16 + ks ; global chunk = quarter*64+c
        size_t so = ((size_t)(quarter * 64 + c)) * 512 + lane * 8;
        gload_lds16(w1frag_h + so, &Wh[c * 64 + lane]);
        gload_lds16(w1frag_l + so, &Wl[c * 64 + lane]);
    }

    f32x4 acc[4][2], acc2[4][2];           // [m][token-group] — static indexing only
    #pragma unroll
    for (int m = 0; m < 4; ++m)
        #pragma unroll
        for (int tg = 0; tg < 2; ++tg) {
            acc[m][tg]  = (f32x4){0.f, 0.f, 0.f, 0.f};
            acc2[m][tg] = (f32x4){0.f, 0.f, 0.f, 0.f};
        }

    // X bases: token-group 0 rows tok0+l15, group 1 rows tok0+16+l15; k = ks*32+lg*8
    const float* xp0 = X + (size_t)(tok0 + l15) * D_DIM + lg * 8;
    const float* xp1 = xp0 + (size_t)16 * D_DIM;

    auto split8 = [&](float4 a, float4 b, half8& hh, half8& ll) {
        float e[8] = {a.x, a.y, a.z, a.w, b.x, b.y, b.z, b.w};
        #pragma unroll
        for (int j = 0; j < 8; ++j) {
            _Float16 h = (_Float16)e[j];
            float r = e[j] - (float)h;
            hh[j] = h;
            ll[j] = (_Float16)(r * 2048.0f);
        }
    };

    // 2-deep X prefetch in NAMED buffers (xvA = even k-steps, xvB = odd) — all static
    float4 xvA[2][2], xvB[2][2];           // [tg][lo/hi]
    xvA[0][0] = *reinterpret_cast<const float4*>(xp0);
    xvA[0][1] = *reinterpret_cast<const float4*>(xp0 + 4);
    xvA[1][0] = *reinterpret_cast<const float4*>(xp1);
    xvA[1][1] = *reinterpret_cast<const float4*>(xp1 + 4);
    xvB[0][0] = *reinterpret_cast<const float4*>(xp0 + 32);
    xvB[0][1] = *reinterpret_cast<const float4*>(xp0 + 36);
    xvB[1][0] = *reinterpret_cast<const float4*>(xp1 + 32);
    xvB[1][1] = *reinterpret_cast<const float4*>(xp1 + 36);

    __syncthreads();                       // W slice ready; ONLY barrier in the kernel

    #pragma unroll 2
    for (int ks2 = 0; ks2 < 16; ks2 += 2) {
        // ---- even step (ks2): consume xvA, refill with ks2+2 ----
        {
            half8 bxh[2], bxl[2];
            split8(xvA[0][0], xvA[0][1], bxh[0], bxl[0]);
            split8(xvA[1][0], xvA[1][1], bxh[1], bxl[1]);
            if (ks2 + 2 < 16) {
                const int ko = (ks2 + 2) * 32;
                xvA[0][0] = *reinterpret_cast<const float4*>(xp0 + ko);
                xvA[0][1] = *reinterpret_cast<const float4*>(xp0 + ko + 4);
                xvA[1][0] = *reinterpret_cast<const float4*>(xp1 + ko);
                xvA[1][1] = *reinterpret_cast<const float4*>(xp1 + ko + 4);
            }
            #pragma unroll
            for (int m = 0; m < 4; ++m) {
                const int c = (m * 16 + ks2) * 64 + lane;
                half8 wh = Wh[c];
                half8 wl = Wl[c];
                #pragma unroll
                for (int tg = 0; tg < 2; ++tg) {
                    acc[m][tg]  = __builtin_amdgcn_mfma_f32_16x16x32_f16(wh, bxh[tg], acc[m][tg],  0, 0, 0);
                    acc2[m][tg] = __builtin_amdgcn_mfma_f32_16x16x32_f16(wh, bxl[tg], acc2[m][tg], 0, 0, 0);
                    acc2[m][tg] = __builtin_amdgcn_mfma_f32_16x16x32_f16(wl, bxh[tg], acc2[m][tg], 0, 0, 0);
                }
            }
        }
        // ---- odd step (ks2+1): consume xvB, refill with ks2+3 ----
        {
            half8 bxh[2], bxl[2];
            split8(xvB[0][0], xvB[0][1], bxh[0], bxl[0]);
            split8(xvB[1][0], xvB[1][1], bxh[1], bxl[1]);
            if (ks2 + 3 < 16) {
                const int ko = (ks2 + 3) * 32;
                xvB[0][0] = *reinterpret_cast<const float4*>(xp0 + ko);
                xvB[0][1] = *reinterpret_cast<const float4*>(xp0 + ko + 4);
                xvB[1][0] = *reinterpret_cast<const float4*>(xp1 + ko);
                xvB[1][1] = *reinterpret_cast<const float4*>(xp1 + ko + 4);
            }
            #pragma unroll
            for (int m = 0; m < 4; ++m) {
                const int c = (m * 16 + ks2 + 1) * 64 + lane;
                half8 wh = Wh[c];
                half8 wl = Wl[c];
                #pragma unroll
                for (int tg = 0; tg < 2; ++tg) {
                    acc[m][tg]  = __builtin_amdgcn_mfma_f32_16x16x32_f16(wh, bxh[tg], acc[m][tg],  0, 0, 0);
                    acc2[m][tg] = __builtin_amdgcn_mfma_f32_16x16x32_f16(wh, bxl[tg], acc2[m][tg], 0, 0, 0);
                    acc2[m][tg] = __builtin_amdgcn_mfma_f32_16x16x32_f16(wl, bxh[tg], acc2[m][tg], 0, 0, 0);
                }
            }
        }
    }

    // ---- epilogue: z = acc + acc2/2048 + b1 ; exact GELU ; dot W2 ; reduce over lg ----
    float part[2] = {0.f, 0.f};
    #pragma unroll
    for (int m = 0; m < 4; ++m) {
        const int col4 = quarter * 64 + m * 16 + lg * 4;
        float4 b1v = *reinterpret_cast<const float4*>(b1 + col4);
        float4 w2v = *reinterpret_cast<const float4*>(W2 + col4);
        float bb[4] = {b1v.x, b1v.y, b1v.z, b1v.w};
        float ww[4] = {w2v.x, w2v.y, w2v.z, w2v.w};
        #pragma unroll
        for (int tg = 0; tg < 2; ++tg)
            #pragma unroll
            for (int r = 0; r < 4; ++r) {
                float z = acc[m][tg][r] + acc2[m][tg][r] * (1.0f / 2048.0f) + bb[r];
                float g = 0.5f * z * (1.0f + erff(z * 0.70710678118654752440f));
                part[tg] = fmaf(g, ww[r], part[tg]);
            }
    }
    #pragma unroll
    for (int tg = 0; tg < 2; ++tg) {
        float v = part[tg];
        v += __shfl_xor(v, 16, 64);
        v += __shfl_xor(v, 32, 64);
        if (lane < 16)
            lp[(size_t)quarter * 65536 + tok0 + tg * 16 + lane] = v;
    }
}

// ---------------- softmax + top-8 + mask/importance/indices (sums 4 lp slices) --------
__global__ __launch_bounds__(256) void softmax_topk_kernel(
    const float* __restrict__ lp,          // (4, 65536)
    const float* __restrict__ b2p,
    const float* __restrict__ base_logits,
    float* __restrict__ out_mask,
    float* __restrict__ out_importance,
    float* __restrict__ out_indices)
{
    const int b = blockIdx.x;
    const int tid = threadIdx.x;
    __shared__ float probs[N_DIM];
    __shared__ float redf[4];
    __shared__ int   redi[4];
    __shared__ int   sel_idx[K_SEL];

    const float b2v = b2p[0];
    int i0g = b * N_DIM + tid;
    int i1g = i0g + 256;
    float l0 = (lp[i0g] + lp[65536 + i0g]) + (lp[131072 + i0g] + lp[196608 + i0g]);
    float l1 = (lp[i1g] + lp[65536 + i1g]) + (lp[131072 + i1g] + lp[196608 + i1g]);
    l0 += b2v + base_logits[tid];
    l1 += b2v + base_logits[tid + 256];

    float m = fmaxf(l0, l1);
    #pragma unroll
    for (int s = 32; s >= 1; s >>= 1) m = fmaxf(m, __shfl_xor(m, s, 64));
    if ((tid & 63) == 0) redf[tid >> 6] = m;
    __syncthreads();
    float gm = fmaxf(fmaxf(redf[0], redf[1]), fmaxf(redf[2], redf[3]));
    __syncthreads();

    float e0 = expf(l0 - gm), e1 = expf(l1 - gm);
    float ssum = e0 + e1;
    #pragma unroll
    for (int s = 32; s >= 1; s >>= 1) ssum += __shfl_xor(ssum, s, 64);
    if ((tid & 63) == 0) redf[tid >> 6] = ssum;
    __syncthreads();
    float denom = redf[0] + redf[1] + redf[2] + redf[3];
    float p0 = e0 / denom, p1 = e1 / denom;
    probs[tid] = p0;
    probs[tid + 256] = p1;
    out_importance[b * N_DIM + tid] = p0;
    out_importance[b * N_DIM + tid + 256] = p1;
    __syncthreads();

    for (int it = 0; it < K_SEL; ++it) {
        float v0 = probs[tid]; int i0 = tid;
        float v1 = probs[tid + 256];
        if (v1 > v0) { v0 = v1; i0 = tid + 256; }
        #pragma unroll
        for (int s = 32; s >= 1; s >>= 1) {
            float ov = __shfl_xor(v0, s, 64);
            int   oi = __shfl_xor(i0, s, 64);
            if (ov > v0 || (ov == v0 && oi < i0)) { v0 = ov; i0 = oi; }
        }
        if ((tid & 63) == 0) { redf[tid >> 6] = v0; redi[tid >> 6] = i0; }
        __syncthreads();
        if (tid == 0) {
            float bv = redf[0]; int bi = redi[0];
            for (int w = 1; w < 4; ++w)
                if (redf[w] > bv || (redf[w] == bv && redi[w] < bi)) { bv = redf[w]; bi = redi[w]; }
            sel_idx[it] = bi;
            probs[bi] = -1.0f;
        }
        __syncthreads();
    }

    float mk0 = 0.f, mk1 = 0.f;
    #pragma unroll
    for (int i = 0; i < K_SEL; ++i) {
        if (sel_idx[i] == tid)       mk0 = 1.f;
        if (sel_idx[i] == tid + 256) mk1 = 1.f;
    }
    out_mask[b * N_DIM + tid] = mk0;
    out_mask[b * N_DIM + tid + 256] = mk1;

    if (tid < K_SEL) out_indices[b * K_SEL + tid] = (float)sel_idx[tid];
}

// ---------------- gather selected rows (overwrites d_out scratch last) ----------------
__global__ __launch_bounds__(256) void gather_kernel(
    const float* __restrict__ X,
    const float* __restrict__ out_indices,
    float* __restrict__ out_selected)
{
    const int b = blockIdx.x;
    const int tid = threadIdx.x;
    __shared__ int sel[K_SEL];
    if (tid < K_SEL) sel[tid] = (int)out_indices[b * K_SEL + tid];
    __syncthreads();
    #pragma unroll
    for (int i = 0; i < 4; ++i) {
        int f = tid + 256 * i;
        int ki = f >> 7;
        int c4 = f & 127;
        float4 v = reinterpret_cast<const float4*>(
            X + ((size_t)b * N_DIM + sel[ki]) * D_DIM)[c4];
        reinterpret_cast<float4*>(
            out_selected + ((size_t)b * K_SEL + ki) * D_DIM)[c4] = v;
    }
}

extern "C" void kernel_launch(void* const* d_in, const int* in_sizes, int n_in,
                              void* d_out, int out_size, void* d_ws, size_t ws_size,
                              hipStream_t stream) {
    const float* X           = (const float*)d_in[0];
    const float* W1          = (const float*)d_in[1];
    const float* b1          = (const float*)d_in[2];
    const float* W2          = (const float*)d_in[3];
    const float* b2          = (const float*)d_in[4];
    const float* base_logits = (const float*)d_in[5];

    float* out            = (float*)d_out;
    float* out_selected   = out;                                  // 128*8*512 = 524288
    float* out_mask       = out_selected + B_DIM * K_SEL * D_DIM; // 128*512
    float* out_importance = out_mask + B_DIM * N_DIM;             // 128*512
    float* out_indices    = out_importance + B_DIM * N_DIM;       // 128*8

    // d_out scratch (gather overwrites out_selected last):
    //   [0      , 262144) lp: 4 x 65536 f32
    //   [262144 , 327680) w1frag_h (131072 halfs)
    //   [327680 , 393216) w1frag_l (131072 halfs)
    float*    lp       = out_selected;
    _Float16* w1frag_h = (_Float16*)(out_selected + 262144);
    _Float16* w1frag_l = (_Float16*)(out_selected + 327680);

    hipLaunchKernelGGL(prep_w1_kernel, dim3(256), dim3(512), 0, stream,
                       W1, w1frag_h, w1frag_l);
    hipLaunchKernelGGL(fused_scorer_wlds, dim3(1024), dim3(512), 0, stream,
                       X, w1frag_h, w1frag_l, b1, W2, lp);
    hipLaunchKernelGGL(softmax_topk_kernel, dim3(B_DIM), dim3(256), 0, stream,
                       lp, b2, base_logits, out_mask, out_importance, out_indices);
    hipLaunchKernelGGL(gather_kernel, dim3(B_DIM), dim3(256), 0, stream,
                       X, out_indices, out_selected);
}